// Round 10
// baseline (957.021 us; speedup 1.0000x reference)
//
#include <hip/hip_runtime.h>

#define TT 512
#define II 8
#define HH 256
#define ST 296   // padded LDS row stride (halfs): 592B, breaks pow2 bank patterns
#define RR 8     // batch rows per block
#define NB 64    // blocks = 512 / RR
#define XSR 136  // xstage row stride in halfs

typedef _Float16 h4_t  __attribute__((ext_vector_type(4)));
typedef _Float16 h8_t  __attribute__((ext_vector_type(8)));
typedef float    f32x2 __attribute__((ext_vector_type(2)));
typedef float    f32x4 __attribute__((ext_vector_type(4)));

__device__ inline h8_t cvt8(const float* __restrict__ p, float s) {
    h8_t r;
#pragma unroll
    for (int i = 0; i < 8; ++i) r[i] = (_Float16)(p[i] * s);
    return r;
}

// R10: W pools move LDS -> global workspace (L2-resident). R9 counters
// (788us = 3693 cyc/step): MFMA pipe 1773 cyc (48%/active-CU, invariant
// ~108 MFMA/SIMD/step for ANY decomposition); the ~1700-cyc gap is the
// CU-shared LDS pipe (~300 LDS instr/CU-step), HALF of it the 16 loop-
// invariant W-pool b128 reads re-read 512 times. Registers can't hold them
// (R8: budget = 128 VGPR + 128 AGPR per wave at (512,2)), but LDS isn't the
// only non-reg home: pre-converted f16 fragments go to d_ws (128 KB, every
// block writes IDENTICAL bytes - benign race; each wave reads only its own
// slice, first read after a vmcnt-draining __syncthreads). In-loop reads
// are global_load_dwordx4 hitting L2 (128KB << 4MB/XCD; ~580 cyc/step L2 BW
// per XCD) on the VMEM pipe - parallel to LDS and MFMA pipes. 1-deep
// explicit prefetch (static idx) hides ~200cyc L2 latency under the 6-MFMA
// blocks; the 2nd wave/SIMD covers the residue. LDS instr/wave ~40 -> ~24.
// Everything else byte-identical to verified R9 (823/788us, absmax 1.95e-3).
// LDS: 18.9K hbuf + 4.25K xstage + 4K predbuf = 27.2K.
__global__ void __launch_bounds__(512, 2) gru_kernel(
    const float* __restrict__ x,    const float* __restrict__ W_ih,
    const float* __restrict__ W_hh, const float* __restrict__ b_ih,
    const float* __restrict__ b_hh, const float* __restrict__ W_lin,
    const float* __restrict__ b_lin, float* __restrict__ out,
    h8_t* __restrict__ ws)
{
    __shared__ _Float16 hbuf[2][16][ST];
    __shared__ _Float16 xstage[2][RR][XSR]; // x windows, double-buffered
    __shared__ float predbuf[2][RR][64];    // pred ring, parity by (p>>6)&1

    const int tid  = threadIdx.x;
    const int w    = tid >> 6;     // wave 0..7
    const int lane = tid & 63;
    const int q    = lane >> 4;    // quad 0..3
    const int r15  = lane & 15;
    const int row0 = blockIdx.x * RR;

    // scales fold log2(e) into the weights:
    //   sigmoid(a) = rcp(1 + exp2(-a*log2e));  tanh(y) = 1 - 2*rcp(1 + exp2(2y*log2e))
    const float sRZ = -1.44269504088896340736f;
    const float sN  =  2.88539008177792681472f;

    const int c0 = w * 32 + r15;
    const int c1 = c0 + 16;

    // ---- W_hh -> B-fragments: 4 chains in regs->AGPR (128); Z1/N1 -> global ws ----
    // ws layout: [g(2)][w(8)][s(8)][lane(64)] h8 = 128 KB. Block-independent
    // addresses; all blocks write identical bytes (idempotent).
    h8_t wfR0[8], wfZ0[8], wfN0[8], wfR1[8];
#pragma unroll
    for (int s = 0; s < 8; ++s) {
        const int k0 = s * 32 + q * 8;
        wfR0[s] = cvt8(W_hh + (size_t)(c0)       * HH + k0, sRZ);
        wfZ0[s] = cvt8(W_hh + (size_t)(256 + c0) * HH + k0, sRZ);
        wfN0[s] = cvt8(W_hh + (size_t)(512 + c0) * HH + k0, sN);
        wfR1[s] = cvt8(W_hh + (size_t)(c1)       * HH + k0, sRZ);
        ws[(size_t)((0 * 8 + w) * 8 + s) * 64 + lane] = cvt8(W_hh + (size_t)(256 + c1) * HH + k0, sRZ);
        ws[(size_t)((1 * 8 + w) * 8 + s) * 64 + lane] = cvt8(W_hh + (size_t)(512 + c1) * HH + k0, sN);
    }
    // ---- x-part B-fragments (16x16x16f16) over [x(8)|bias(1)|0..] ----
    h4_t xfR[2], xfZ[2], xfN[2];
#pragma unroll
    for (int g = 0; g < 2; ++g) {
        const int cR = g ? c1 : c0;
#pragma unroll
        for (int j = 0; j < 4; ++j) {
            const int kp = q * 4 + j;
            float vR = 0.f, vZ = 0.f, vN = 0.f;
            if (kp < 8) {
                vR = W_ih[(cR)       * II + kp] * sRZ;
                vZ = W_ih[(256 + cR) * II + kp] * sRZ;
                vN = W_ih[(512 + cR) * II + kp] * sN;
            } else if (kp == 8) {
                vR = (b_ih[cR]       + b_hh[cR])       * sRZ;
                vZ = (b_ih[256 + cR] + b_hh[256 + cR]) * sRZ;
                vN = b_ih[512 + cR] * sN;   // b_hh_n rides inside r*(.), kept separate
            }
            xfR[g][j] = (_Float16)vR; xfZ[g][j] = (_Float16)vZ; xfN[g][j] = (_Float16)vN;
        }
    }
    const bool hi = (lane >= 32);
    const float bhnp = (hi ? b_hh[512 + c1] : b_hh[512 + c0]) * sN;
    const float blin = b_lin[0];
    const float wl0 = W_lin[lane * 4 + 0], wl1 = W_lin[lane * 4 + 1];
    const float wl2 = W_lin[lane * 4 + 2], wl3 = W_lin[lane * 4 + 3];

    const h4_t bias4 = {(_Float16)1.f, (_Float16)0.f, (_Float16)0.f, (_Float16)0.f};
    const h4_t zero4 = {(_Float16)0.f, (_Float16)0.f, (_Float16)0.f, (_Float16)0.f};

    // ---- LDS init: zero h buffers; preload x window 0 (steps 0..15) ----
    for (int i = tid; i < 2 * 16 * ST; i += 512) (&hbuf[0][0][0])[i] = (_Float16)0.f;
    const int xrow = tid >> 6, xf2 = (tid & 63) * 2;
    {
        const f32x2 v = *(const f32x2*)(x + (size_t)(row0 + xrow) * TT * II + xf2);
        xstage[0][xrow][xf2]     = (_Float16)v[0];
        xstage[0][xrow][xf2 + 1] = (_Float16)v[1];
    }
    __syncthreads();   // drains vmcnt(0): ws writes complete before first read

    // per-wave ws read pointers (lane-private, loop-invariant addresses)
    const h8_t* __restrict__ wz_g = ws + (size_t)((0 * 8 + w) * 8) * 64 + lane;
    const h8_t* __restrict__ wn_g = ws + (size_t)((1 * 8 + w) * 8) * 64 + lane;

    f32x4 hreg = {0.f, 0.f, 0.f, 0.f};
    const f32x4 z4 = {0.f, 0.f, 0.f, 0.f};

    const int rb   = (q & 1) * 4;
    const int colp = hi ? c1 : c0;

    // hoisted pointer pairs (selected by compile-time ti&1 after unroll)
    const _Float16* __restrict__ hbA0 = &hbuf[0][r15][0];
    const _Float16* __restrict__ hbA1 = &hbuf[1][r15][0];
    const _Float16* __restrict__ pr0  = &hbuf[0][w][lane * 4];
    const _Float16* __restrict__ pr1  = &hbuf[1][w][lane * 4];
    _Float16* __restrict__ hw0 = &hbuf[0][rb][colp];
    _Float16* __restrict__ hw1 = &hbuf[1][rb][colp];
    const _Float16* __restrict__ xsl0 = &xstage[0][r15 & 7][(q & 1) * 4];
    const _Float16* __restrict__ xsl1 = &xstage[1][r15 & 7][(q & 1) * 4];
    _Float16* __restrict__ xw0 = &xstage[0][xrow][xf2];
    _Float16* __restrict__ xw1 = &xstage[1][xrow][xf2];
    const float* __restrict__ xrp = x + ((size_t)(row0 + xrow) * TT + 16) * II + xf2;

    for (int tw = 0; tw < 32; ++tw) {
        const _Float16* __restrict__ xs_rd = (tw & 1) ? xsl1 : xsl0;
        _Float16* __restrict__ xs_wr = (tw & 1) ? xw0 : xw1;   // other buffer

        // window refill: one load, consumed at ti==15
        f32x2 xpre = {0.f, 0.f};
        if (tw < 31) xpre = *(const f32x2*)xrp;

#pragma unroll
        for (int ti = 0; ti < 16; ++ti) {
            const int t = tw * 16 + ti;
            const int cur = ti & 1;

            // issue first W frags early (L2 hit ~200cyc; small MFMAs cover)
            h8_t wzc = wz_g[0];
            h8_t wnc = wn_g[0];

            const _Float16* __restrict__ hb = cur ? hbA1 : hbA0;
            const h4_t xa = *(const h4_t*)(xs_rd + ti * 8);
            const h4_t a2 = (q < 2) ? xa : ((q == 2) ? bias4 : zero4);
            f32x4 accR0 = __builtin_amdgcn_mfma_f32_16x16x16f16(a2, xfR[0], z4, 0, 0, 0);
            f32x4 accZ0 = __builtin_amdgcn_mfma_f32_16x16x16f16(a2, xfZ[0], z4, 0, 0, 0);
            f32x4 gin0  = __builtin_amdgcn_mfma_f32_16x16x16f16(a2, xfN[0], z4, 0, 0, 0);
            f32x4 accR1 = __builtin_amdgcn_mfma_f32_16x16x16f16(a2, xfR[1], z4, 0, 0, 0);
            f32x4 accZ1 = __builtin_amdgcn_mfma_f32_16x16x16f16(a2, xfZ[1], z4, 0, 0, 0);
            f32x4 gin1  = __builtin_amdgcn_mfma_f32_16x16x16f16(a2, xfN[1], z4, 0, 0, 0);
            f32x4 accN0 = z4, accN1 = z4;
#pragma unroll
            for (int s = 0; s < 8; ++s) {
                // 1-deep prefetch: issue s+1 loads before s's MFMAs (static idx)
                h8_t wzn_v, wnn_v;
                if (s < 7) { wzn_v = wz_g[(s + 1) * 64]; wnn_v = wn_g[(s + 1) * 64]; }
                const h8_t a = *(const h8_t*)(hb + s * 32 + q * 8);
                accR0 = __builtin_amdgcn_mfma_f32_16x16x32_f16(a, wfR0[s], accR0, 0, 0, 0);
                accZ0 = __builtin_amdgcn_mfma_f32_16x16x32_f16(a, wfZ0[s], accZ0, 0, 0, 0);
                accN0 = __builtin_amdgcn_mfma_f32_16x16x32_f16(a, wfN0[s], accN0, 0, 0, 0);
                accR1 = __builtin_amdgcn_mfma_f32_16x16x32_f16(a, wfR1[s], accR1, 0, 0, 0);
                accZ1 = __builtin_amdgcn_mfma_f32_16x16x32_f16(a, wzc,    accZ1, 0, 0, 0);
                accN1 = __builtin_amdgcn_mfma_f32_16x16x32_f16(a, wnc,    accN1, 0, 0, 0);
                if (s < 7) { wzc = wzn_v; wnc = wnn_v; }
            }

            // pred_{t-1} from hbuf[cur] (overlaps MFMA drain) -> LDS ring
            if (t > 0) {
                const h4_t hv4 = *(const h4_t*)(cur ? pr1 : pr0);
                float s0 = (float)hv4[0] * wl0 + (float)hv4[1] * wl1
                         + (float)hv4[2] * wl2 + (float)hv4[3] * wl3;
#pragma unroll
                for (int m = 32; m >= 1; m >>= 1) s0 += __shfl_xor(s0, m, 64);
                if (lane == 0) predbuf[((t - 1) >> 6) & 1][w][(t - 1) & 63] = s0 + blin;
            }

            // gates, dense packed (lanes 0-31 g0, 32-63 g1)
            _Float16* __restrict__ hw = cur ? hw0 : hw1;   // writes to buffer nxt=cur^1
#pragma unroll
            for (int j = 0; j < 4; ++j) {
                const float vR = hi ? accR1[j] : accR0[j];
                const float vZ = hi ? accZ1[j] : accZ0[j];
                const float vN = hi ? accN1[j] : accN0[j];
                const float vG = hi ? gin1[j]  : gin0[j];
                const float rr = __builtin_amdgcn_rcpf(1.f + __builtin_amdgcn_exp2f(vR));
                const float zz = __builtin_amdgcn_rcpf(1.f + __builtin_amdgcn_exp2f(vZ));
                const float u  = vG + rr * (vN + bhnp);
                const float nn = 1.f - 2.f * __builtin_amdgcn_rcpf(1.f + __builtin_amdgcn_exp2f(u));
                const float hv = nn + zz * (hreg[j] - nn);
                hreg[j] = hv;
                const _Float16 hh = (_Float16)hv;
                hw[j * ST]          = hh;
                hw[j * ST + 8 * ST] = hh;   // mirror rows 8-15
            }

            // x window writeback into the other buffer (load issued at tw start)
            if (ti == 15 && tw < 31) {
                xs_wr[0] = (_Float16)xpre[0];
                xs_wr[1] = (_Float16)xpre[1];
            }

            __syncthreads();   // single barrier per step

            // coalesced pred flush: one 2KB store per 64 steps
            if (ti == 0 && (tw & 3) == 0 && tw > 0) {
                const int pb = ((t >> 6) & 1) ^ 1;
                out[(size_t)(row0 + (tid >> 6)) * TT + (t - 64) + (tid & 63)] =
                    predbuf[pb][tid >> 6][tid & 63];
            }
        }
        xrp += 16 * II;
    }

    // final pred for t = TT-1 (h_final sits in hbuf[0])
    {
        const h4_t hv4 = *(const h4_t*)pr0;
        float s0 = (float)hv4[0] * wl0 + (float)hv4[1] * wl1
                 + (float)hv4[2] * wl2 + (float)hv4[3] * wl3;
#pragma unroll
        for (int m = 32; m >= 1; m >>= 1) s0 += __shfl_xor(s0, m, 64);
        if (lane == 0) predbuf[1][w][63] = s0 + blin;
    }
    __syncthreads();
    // flush last chunk [448, 512)
    out[(size_t)(row0 + (tid >> 6)) * TT + 448 + (tid & 63)] =
        predbuf[1][tid >> 6][tid & 63];
}

extern "C" void kernel_launch(void* const* d_in, const int* in_sizes, int n_in,
                              void* d_out, int out_size, void* d_ws, size_t ws_size,
                              hipStream_t stream) {
    const float* x     = (const float*)d_in[0];
    const float* W_ih  = (const float*)d_in[1];
    const float* W_hh  = (const float*)d_in[2];
    const float* b_ih  = (const float*)d_in[3];
    const float* b_hh  = (const float*)d_in[4];
    const float* W_lin = (const float*)d_in[5];
    const float* b_lin = (const float*)d_in[6];
    float* out = (float*)d_out;
    // ws: 2*8*8*64 h8 fragments = 128 KiB of workspace for the Z1/N1 W pools
    gru_kernel<<<NB, 512, 0, stream>>>(x, W_ih, W_hh, b_ih, b_hh, W_lin, b_lin, out,
                                       (h8_t*)d_ws);
}

// Round 11
// 893.980 us; speedup vs baseline: 1.0705x; 1.0705x over previous
//
#include <hip/hip_runtime.h>

#define TT 512
#define II 8
#define HH 256
#define ST 296   // padded LDS row stride (halfs): 592B, breaks pow2 bank patterns
#define RR 8     // batch rows per block
#define NB 64    // blocks = 512 / RR
#define XSR 136  // xstage row stride in halfs

typedef _Float16 h4_t  __attribute__((ext_vector_type(4)));
typedef _Float16 h8_t  __attribute__((ext_vector_type(8)));
typedef float    f32x2 __attribute__((ext_vector_type(2)));
typedef float    f32x4 __attribute__((ext_vector_type(4)));

__device__ inline h8_t cvt8(const float* __restrict__ p, float s) {
    h8_t r;
#pragma unroll
    for (int i = 0; i < 8; ++i) r[i] = (_Float16)(p[i] * s);
    return r;
}

// DPP add (compiler-scheduled, hazard-safe — unlike raw asm, cf. R4 failure).
// old=0 + bound_ctrl=false => invalid lanes contribute 0 to the sum.
template <int CTRL>
__device__ __forceinline__ float dpp_add(float v) {
    int s = __builtin_amdgcn_update_dpp(0, __builtin_bit_cast(int, v), CTRL, 0xf, 0xf, false);
    return v + __builtin_bit_cast(float, s);
}
// wave64 sum -> lane 63: row_shr 1,2,4,8 then row_bcast:15, row_bcast:31
__device__ __forceinline__ float wave_sum64(float v) {
    v = dpp_add<0x111>(v);  // row_shr:1
    v = dpp_add<0x112>(v);  // row_shr:2
    v = dpp_add<0x114>(v);  // row_shr:4
    v = dpp_add<0x118>(v);  // row_shr:8   -> lane15 of each row holds row sum
    v = dpp_add<0x142>(v);  // row_bcast:15
    v = dpp_add<0x143>(v);  // row_bcast:31 -> lane 63 holds total
    return v;
}

// R11: overlap the serial phases. R9 (788us = 3693 cyc/step): MFMA 1978 +
// VALU 1348 + LDS ~2900 execute mostly SERIALLY because (a) gate selects
// need the last MFMA chain, (b) lockstep waves hit each pipe together.
// R10 (-> 933us) proved W-via-L2 fails with only ~116 cyc issue-to-use cover.
//  - Phase-split R->Z->N, A-frags in regs (read once): eR/rr/eZ gate slices
//    are independent of later chains -> fill the ~18 idle issue slots per
//    MFMA; Z1 W-frags load from L2 ws at R-phase START (cover ~350 cyc >
//    L2 latency — R10's fix); N1 stays in LDS.
//  - h mirror writes deleted: A-reads alias rows 8-15 -> 0-7 via (r15&7),
//    the exact idiom already verified for xstage in R9. hbuf -> [2][8][ST].
//  - pred reduce via DPP (VALU) instead of 6 ds_swizzle (LDS pipe at ~81%).
// LDS b128/wave/step: 24 -> 16; LDS total 83.5K; chain order s=0..7
// unchanged -> numerics identical to R9.
__global__ void __launch_bounds__(512, 2) gru_kernel(
    const float* __restrict__ x,    const float* __restrict__ W_ih,
    const float* __restrict__ W_hh, const float* __restrict__ b_ih,
    const float* __restrict__ b_hh, const float* __restrict__ W_lin,
    const float* __restrict__ b_lin, float* __restrict__ out,
    h8_t* __restrict__ ws)
{
    __shared__ _Float16 hbuf[2][RR][ST];    // 9.5K: h double-buffer, 8 rows
    __shared__ h8_t wn1buf[8 * 8 * 64];     // 64K: N1 W frags, lane-private
    __shared__ _Float16 xstage[2][RR][XSR]; // 4.25K: x windows
    __shared__ float predbuf[2][RR][64];    // 4K: pred ring

    const int tid  = threadIdx.x;
    const int w    = tid >> 6;     // wave 0..7
    const int lane = tid & 63;
    const int q    = lane >> 4;    // quad 0..3
    const int r15  = lane & 15;
    const int row0 = blockIdx.x * RR;

    const float sRZ = -1.44269504088896340736f;
    const float sN  =  2.88539008177792681472f;

    const int c0 = w * 32 + r15;
    const int c1 = c0 + 16;

    // ---- W_hh: R0,Z0,N0,R1 -> regs (128 AGPR); Z1 -> global ws; N1 -> LDS ----
    h8_t wfR0[8], wfZ0[8], wfN0[8], wfR1[8];
#pragma unroll
    for (int s = 0; s < 8; ++s) {
        const int k0 = s * 32 + q * 8;
        wfR0[s] = cvt8(W_hh + (size_t)(c0)       * HH + k0, sRZ);
        wfZ0[s] = cvt8(W_hh + (size_t)(256 + c0) * HH + k0, sRZ);
        wfN0[s] = cvt8(W_hh + (size_t)(512 + c0) * HH + k0, sN);
        wfR1[s] = cvt8(W_hh + (size_t)(c1)       * HH + k0, sRZ);
        ws[(size_t)(w * 8 + s) * 64 + lane]     = cvt8(W_hh + (size_t)(256 + c1) * HH + k0, sRZ); // Z1
        wn1buf[(w * 8 + s) * 64 + lane]         = cvt8(W_hh + (size_t)(512 + c1) * HH + k0, sN);  // N1
    }
    // ---- x-part B-fragments over [x(8)|bias(1)|0..] ----
    h4_t xfR[2], xfZ[2], xfN[2];
#pragma unroll
    for (int g = 0; g < 2; ++g) {
        const int cR = g ? c1 : c0;
#pragma unroll
        for (int j = 0; j < 4; ++j) {
            const int kp = q * 4 + j;
            float vR = 0.f, vZ = 0.f, vN = 0.f;
            if (kp < 8) {
                vR = W_ih[(cR)       * II + kp] * sRZ;
                vZ = W_ih[(256 + cR) * II + kp] * sRZ;
                vN = W_ih[(512 + cR) * II + kp] * sN;
            } else if (kp == 8) {
                vR = (b_ih[cR]       + b_hh[cR])       * sRZ;
                vZ = (b_ih[256 + cR] + b_hh[256 + cR]) * sRZ;
                vN = b_ih[512 + cR] * sN;
            }
            xfR[g][j] = (_Float16)vR; xfZ[g][j] = (_Float16)vZ; xfN[g][j] = (_Float16)vN;
        }
    }
    const bool hi = (lane >= 32);
    const float bhnp = (hi ? b_hh[512 + c1] : b_hh[512 + c0]) * sN;
    const float blin = b_lin[0];
    const float wl0 = W_lin[lane * 4 + 0], wl1 = W_lin[lane * 4 + 1];
    const float wl2 = W_lin[lane * 4 + 2], wl3 = W_lin[lane * 4 + 3];

    const h4_t bias4 = {(_Float16)1.f, (_Float16)0.f, (_Float16)0.f, (_Float16)0.f};
    const h4_t zero4 = {(_Float16)0.f, (_Float16)0.f, (_Float16)0.f, (_Float16)0.f};

    // ---- LDS init + x window 0 preload ----
    for (int i = tid; i < 2 * RR * ST; i += 512) (&hbuf[0][0][0])[i] = (_Float16)0.f;
    const int xrow = tid >> 6, xf2 = (tid & 63) * 2;
    {
        const f32x2 v = *(const f32x2*)(x + (size_t)(row0 + xrow) * TT * II + xf2);
        xstage[0][xrow][xf2]     = (_Float16)v[0];
        xstage[0][xrow][xf2 + 1] = (_Float16)v[1];
    }
    __syncthreads();   // drains vmcnt(0): ws writes complete before first read

    const h8_t* __restrict__ wz_g   = ws + (size_t)(w * 8) * 64 + lane;       // L2
    const h8_t* __restrict__ wn_l   = &wn1buf[w * 8 * 64 + lane];             // LDS

    f32x4 hreg = {0.f, 0.f, 0.f, 0.f};
    const f32x4 z4 = {0.f, 0.f, 0.f, 0.f};

    const int rb   = (q & 1) * 4;
    const int colp = hi ? c1 : c0;
    const int ar   = r15 & 7;          // aliased A-row
    const float* __restrict__ xrp = x + ((size_t)(row0 + xrow) * TT + 16) * II + xf2;

    for (int tw = 0; tw < 32; ++tw) {
        const int win = tw & 1;
        // window refill: one load, consumed at ti==15
        f32x2 xpre = {0.f, 0.f};
        if (tw < 31) xpre = *(const f32x2*)xrp;

#pragma unroll
        for (int ti = 0; ti < 16; ++ti) {
            const int t = tw * 16 + ti;
            const int cur = ti & 1, nxt = cur ^ 1;

            // issue Z1 W loads first (L2-hot; consumed in Z phase, ~350cyc away)
            h8_t wzv[8];
#pragma unroll
            for (int s = 0; s < 8; ++s) wzv[s] = wz_g[s * 64];

            // A-frags -> regs (read once, serve all 3 phases)
            h8_t a[8];
#pragma unroll
            for (int s = 0; s < 8; ++s)
                a[s] = *(const h8_t*)&hbuf[cur][ar][s * 32 + q * 8];
            const h4_t xa = *(const h4_t*)&xstage[win][ar][ti * 8 + (q & 1) * 4];
            const h4_t a2 = (q < 2) ? xa : ((q == 2) ? bias4 : zero4);

            // ---- R phase ----
            f32x4 accR0 = __builtin_amdgcn_mfma_f32_16x16x16f16(a2, xfR[0], z4, 0, 0, 0);
            f32x4 accR1 = __builtin_amdgcn_mfma_f32_16x16x16f16(a2, xfR[1], z4, 0, 0, 0);
#pragma unroll
            for (int s = 0; s < 8; ++s) {
                accR0 = __builtin_amdgcn_mfma_f32_16x16x32_f16(a[s], wfR0[s], accR0, 0, 0, 0);
                accR1 = __builtin_amdgcn_mfma_f32_16x16x32_f16(a[s], wfR1[s], accR1, 0, 0, 0);
            }
            // gate slice 1 (independent of Z/N chains -> fills MFMA issue gaps)
            float eR[4];
#pragma unroll
            for (int j = 0; j < 4; ++j)
                eR[j] = __builtin_amdgcn_exp2f(hi ? accR1[j] : accR0[j]);

            // pred_{t-1} (reads stable hbuf[cur]; VALU-only DPP reduce)
            if (t > 0) {
                const h4_t hv4 = *(const h4_t*)&hbuf[cur][w][lane * 4];
                float s0 = (float)hv4[0] * wl0 + (float)hv4[1] * wl1
                         + (float)hv4[2] * wl2 + (float)hv4[3] * wl3;
                s0 = wave_sum64(s0);
                if (lane == 63) predbuf[((t - 1) >> 6) & 1][w][(t - 1) & 63] = s0 + blin;
            }

            // ---- Z phase (Z1 from L2 regs) ----
            f32x4 accZ0 = __builtin_amdgcn_mfma_f32_16x16x16f16(a2, xfZ[0], z4, 0, 0, 0);
            f32x4 accZ1 = __builtin_amdgcn_mfma_f32_16x16x16f16(a2, xfZ[1], z4, 0, 0, 0);
#pragma unroll
            for (int s = 0; s < 8; ++s) {
                accZ0 = __builtin_amdgcn_mfma_f32_16x16x32_f16(a[s], wfZ0[s], accZ0, 0, 0, 0);
                accZ1 = __builtin_amdgcn_mfma_f32_16x16x32_f16(a[s], wzv[s],  accZ1, 0, 0, 0);
            }
            // gate slice 2
            float rr_[4], eZ[4];
#pragma unroll
            for (int j = 0; j < 4; ++j) {
                rr_[j] = __builtin_amdgcn_rcpf(1.f + eR[j]);
                eZ[j]  = __builtin_amdgcn_exp2f(hi ? accZ1[j] : accZ0[j]);
            }

            // ---- N phase (N1 from LDS) ----
            f32x4 gin0 = __builtin_amdgcn_mfma_f32_16x16x16f16(a2, xfN[0], z4, 0, 0, 0);
            f32x4 gin1 = __builtin_amdgcn_mfma_f32_16x16x16f16(a2, xfN[1], z4, 0, 0, 0);
            f32x4 accN0 = z4, accN1 = z4;
#pragma unroll
            for (int s = 0; s < 8; ++s) {
                accN0 = __builtin_amdgcn_mfma_f32_16x16x32_f16(a[s], wfN0[s],      accN0, 0, 0, 0);
                accN1 = __builtin_amdgcn_mfma_f32_16x16x32_f16(a[s], wn_l[s * 64], accN1, 0, 0, 0);
            }

            // gate tail + h write (no mirror: A-reads alias rows 8-15 -> 0-7)
#pragma unroll
            for (int j = 0; j < 4; ++j) {
                const float zz = __builtin_amdgcn_rcpf(1.f + eZ[j]);
                const float vN = hi ? accN1[j] : accN0[j];
                const float vG = hi ? gin1[j]  : gin0[j];
                const float u  = vG + rr_[j] * (vN + bhnp);
                const float nn = 1.f - 2.f * __builtin_amdgcn_rcpf(1.f + __builtin_amdgcn_exp2f(u));
                const float hv = nn + zz * (hreg[j] - nn);
                hreg[j] = hv;
                hbuf[nxt][rb + j][colp] = (_Float16)hv;
            }

            // x window writeback (load issued at tw start; vmcnt hidden)
            if (ti == 15 && tw < 31) {
                xstage[win ^ 1][xrow][xf2]     = (_Float16)xpre[0];
                xstage[win ^ 1][xrow][xf2 + 1] = (_Float16)xpre[1];
            }

            __syncthreads();   // single barrier per step

            // coalesced pred flush: one 2KB store per 64 steps
            if (ti == 0 && (tw & 3) == 0 && tw > 0) {
                const int pb = ((t >> 6) & 1) ^ 1;
                out[(size_t)(row0 + (tid >> 6)) * TT + (t - 64) + (tid & 63)] =
                    predbuf[pb][tid >> 6][tid & 63];
            }
        }
        xrp += 16 * II;
    }

    // final pred for t = TT-1 (h_final in hbuf[0])
    {
        const h4_t hv4 = *(const h4_t*)&hbuf[0][w][lane * 4];
        float s0 = (float)hv4[0] * wl0 + (float)hv4[1] * wl1
                 + (float)hv4[2] * wl2 + (float)hv4[3] * wl3;
        s0 = wave_sum64(s0);
        if (lane == 63) predbuf[1][w][63] = s0 + blin;
    }
    __syncthreads();
    // flush last chunk [448, 512)
    out[(size_t)(row0 + (tid >> 6)) * TT + 448 + (tid & 63)] =
        predbuf[1][tid >> 6][tid & 63];
}

extern "C" void kernel_launch(void* const* d_in, const int* in_sizes, int n_in,
                              void* d_out, int out_size, void* d_ws, size_t ws_size,
                              hipStream_t stream) {
    const float* x     = (const float*)d_in[0];
    const float* W_ih  = (const float*)d_in[1];
    const float* W_hh  = (const float*)d_in[2];
    const float* b_ih  = (const float*)d_in[3];
    const float* b_hh  = (const float*)d_in[4];
    const float* W_lin = (const float*)d_in[5];
    const float* b_lin = (const float*)d_in[6];
    float* out = (float*)d_out;
    // ws: 8*8*64 h8 fragments = 64 KiB (Z1 W pool, L2-resident)
    gru_kernel<<<NB, 512, 0, stream>>>(x, W_ih, W_hh, b_ih, b_hh, W_lin, b_lin, out,
                                       (h8_t*)d_ws);
}

// Round 12
// 760.271 us; speedup vs baseline: 1.2588x; 1.1759x over previous
//
#include <hip/hip_runtime.h>

#define TT 512
#define II 8
#define HH 256
#define ST 296   // padded LDS row stride (halfs): 592B, breaks pow2 bank patterns
#define RR 8     // batch rows per block
#define NB 64    // blocks = 512 / RR
#define XSR 136  // xstage row stride in halfs

typedef _Float16 h4_t  __attribute__((ext_vector_type(4)));
typedef _Float16 h8_t  __attribute__((ext_vector_type(8)));
typedef float    f32x2 __attribute__((ext_vector_type(2)));
typedef float    f32x4 __attribute__((ext_vector_type(4)));

__device__ inline h8_t cvt8(const float* __restrict__ p, float s) {
    h8_t r;
#pragma unroll
    for (int i = 0; i < 8; ++i) r[i] = (_Float16)(p[i] * s);
    return r;
}

// DPP add (compiler-scheduled, hazard-safe). old=0, bound_ctrl=false.
template <int CTRL>
__device__ __forceinline__ float dpp_add(float v) {
    int s = __builtin_amdgcn_update_dpp(0, __builtin_bit_cast(int, v), CTRL, 0xf, 0xf, false);
    return v + __builtin_bit_cast(float, s);
}
__device__ __forceinline__ float wave_sum64(float v) {
    v = dpp_add<0x111>(v);  // row_shr:1
    v = dpp_add<0x112>(v);  // row_shr:2
    v = dpp_add<0x114>(v);  // row_shr:4
    v = dpp_add<0x118>(v);  // row_shr:8
    v = dpp_add<0x142>(v);  // row_bcast:15
    v = dpp_add<0x143>(v);  // row_bcast:31 -> lane 63 holds total
    return v;
}

// R12: R9's fused 6-chain interleave (the thing R11's phase-split broke:
// 3 chain-drain points cost ~750 cyc/step, MfmaUtil 12->10.8) + the
// verified R11 side-wins (no-mirror alias, DPP pred) + Z1 W-frags in
// registers REFRESHED FROM L2 ACROSS THE BARRIER:
//  - consume wzv[8] (loaded during the previous step) inside the fused
//    MFMA loop: zero wait, the barrier's vmcnt(0) already drained them;
//  - reissue the 8 loads right AFTER the MFMA loop: the ~300cyc gate tail
//    covers L2 latency (~200), so the barrier drain costs ~0 (R10's cover
//    bug fixed); the barrier is a memory fence -> no load-CSE, no sinking.
// LDS/CU-step: ~2400 -> ~1650 (W-pool b128s halved), now below the ~2100
// MFMA term. N1 stays in LDS (VGPR budget: ~110 < 128; wzv = +32).
// LDS: 9.5K hbuf + 64K wn1buf + 4.25K xstage + 4K predbuf = 81.7K.
__global__ void __launch_bounds__(512, 2) gru_kernel(
    const float* __restrict__ x,    const float* __restrict__ W_ih,
    const float* __restrict__ W_hh, const float* __restrict__ b_ih,
    const float* __restrict__ b_hh, const float* __restrict__ W_lin,
    const float* __restrict__ b_lin, float* __restrict__ out,
    h8_t* __restrict__ ws)
{
    __shared__ _Float16 hbuf[2][RR][ST];    // 9.5K: h double-buffer, 8 rows
    __shared__ h8_t wn1buf[8 * 8 * 64];     // 64K: N1 W frags, lane-private
    __shared__ _Float16 xstage[2][RR][XSR]; // 4.25K: x windows
    __shared__ float predbuf[2][RR][64];    // 4K: pred ring

    const int tid  = threadIdx.x;
    const int w    = tid >> 6;     // wave 0..7
    const int lane = tid & 63;
    const int q    = lane >> 4;    // quad 0..3
    const int r15  = lane & 15;
    const int row0 = blockIdx.x * RR;

    const float sRZ = -1.44269504088896340736f;
    const float sN  =  2.88539008177792681472f;

    const int c0 = w * 32 + r15;
    const int c1 = c0 + 16;

    // ---- W_hh: R0,Z0,N0,R1 -> regs (128 AGPR); Z1 -> global ws; N1 -> LDS ----
    h8_t wfR0[8], wfZ0[8], wfN0[8], wfR1[8];
#pragma unroll
    for (int s = 0; s < 8; ++s) {
        const int k0 = s * 32 + q * 8;
        wfR0[s] = cvt8(W_hh + (size_t)(c0)       * HH + k0, sRZ);
        wfZ0[s] = cvt8(W_hh + (size_t)(256 + c0) * HH + k0, sRZ);
        wfN0[s] = cvt8(W_hh + (size_t)(512 + c0) * HH + k0, sN);
        wfR1[s] = cvt8(W_hh + (size_t)(c1)       * HH + k0, sRZ);
        ws[(size_t)(w * 8 + s) * 64 + lane] = cvt8(W_hh + (size_t)(256 + c1) * HH + k0, sRZ); // Z1
        wn1buf[(w * 8 + s) * 64 + lane]     = cvt8(W_hh + (size_t)(512 + c1) * HH + k0, sN);  // N1
    }
    // ---- x-part B-fragments over [x(8)|bias(1)|0..] ----
    h4_t xfR[2], xfZ[2], xfN[2];
#pragma unroll
    for (int g = 0; g < 2; ++g) {
        const int cR = g ? c1 : c0;
#pragma unroll
        for (int j = 0; j < 4; ++j) {
            const int kp = q * 4 + j;
            float vR = 0.f, vZ = 0.f, vN = 0.f;
            if (kp < 8) {
                vR = W_ih[(cR)       * II + kp] * sRZ;
                vZ = W_ih[(256 + cR) * II + kp] * sRZ;
                vN = W_ih[(512 + cR) * II + kp] * sN;
            } else if (kp == 8) {
                vR = (b_ih[cR]       + b_hh[cR])       * sRZ;
                vZ = (b_ih[256 + cR] + b_hh[256 + cR]) * sRZ;
                vN = b_ih[512 + cR] * sN;
            }
            xfR[g][j] = (_Float16)vR; xfZ[g][j] = (_Float16)vZ; xfN[g][j] = (_Float16)vN;
        }
    }
    const bool hi = (lane >= 32);
    const float bhnp = (hi ? b_hh[512 + c1] : b_hh[512 + c0]) * sN;
    const float blin = b_lin[0];
    const float wl0 = W_lin[lane * 4 + 0], wl1 = W_lin[lane * 4 + 1];
    const float wl2 = W_lin[lane * 4 + 2], wl3 = W_lin[lane * 4 + 3];

    const h4_t bias4 = {(_Float16)1.f, (_Float16)0.f, (_Float16)0.f, (_Float16)0.f};
    const h4_t zero4 = {(_Float16)0.f, (_Float16)0.f, (_Float16)0.f, (_Float16)0.f};

    // ---- LDS init + x window 0 preload ----
    for (int i = tid; i < 2 * RR * ST; i += 512) (&hbuf[0][0][0])[i] = (_Float16)0.f;
    const int xrow = tid >> 6, xf2 = (tid & 63) * 2;
    {
        const f32x2 v = *(const f32x2*)(x + (size_t)(row0 + xrow) * TT * II + xf2);
        xstage[0][xrow][xf2]     = (_Float16)v[0];
        xstage[0][xrow][xf2 + 1] = (_Float16)v[1];
    }
    __syncthreads();   // drains vmcnt(0): ws writes complete before first read

    const h8_t* __restrict__ wz_g = ws + (size_t)(w * 8) * 64 + lane;   // L2
    const h8_t* __restrict__ wn_l = &wn1buf[w * 8 * 64 + lane];         // LDS

    // prologue: first wzv fill (L2-hot after the ws writes)
    h8_t wzv[8];
#pragma unroll
    for (int s = 0; s < 8; ++s) wzv[s] = wz_g[s * 64];

    f32x4 hreg = {0.f, 0.f, 0.f, 0.f};
    const f32x4 z4 = {0.f, 0.f, 0.f, 0.f};

    const int rb   = (q & 1) * 4;
    const int colp = hi ? c1 : c0;
    const int ar   = r15 & 7;          // aliased A-row (rows 8-15 -> 0-7)

    // hoisted pointer pairs (selected by compile-time ti&1 after unroll)
    const _Float16* __restrict__ hbA0 = &hbuf[0][ar][0];
    const _Float16* __restrict__ hbA1 = &hbuf[1][ar][0];
    const _Float16* __restrict__ pr0  = &hbuf[0][w][lane * 4];
    const _Float16* __restrict__ pr1  = &hbuf[1][w][lane * 4];
    _Float16* __restrict__ hw0 = &hbuf[0][rb][colp];
    _Float16* __restrict__ hw1 = &hbuf[1][rb][colp];
    const _Float16* __restrict__ xsl0 = &xstage[0][ar][(q & 1) * 4];
    const _Float16* __restrict__ xsl1 = &xstage[1][ar][(q & 1) * 4];
    _Float16* __restrict__ xw0 = &xstage[0][xrow][xf2];
    _Float16* __restrict__ xw1 = &xstage[1][xrow][xf2];
    const float* __restrict__ xrp = x + ((size_t)(row0 + xrow) * TT + 16) * II + xf2;

    for (int tw = 0; tw < 32; ++tw) {
        const _Float16* __restrict__ xs_rd = (tw & 1) ? xsl1 : xsl0;
        _Float16* __restrict__ xs_wr = (tw & 1) ? xw0 : xw1;   // other buffer

        // window refill: one load, consumed at ti==15
        f32x2 xpre = {0.f, 0.f};
        if (tw < 31) xpre = *(const f32x2*)xrp;

#pragma unroll
        for (int ti = 0; ti < 16; ++ti) {
            const int t = tw * 16 + ti;
            const int cur = ti & 1;

            const _Float16* __restrict__ hb = cur ? hbA1 : hbA0;
            const h4_t xa = *(const h4_t*)(xs_rd + ti * 8);
            const h4_t a2 = (q < 2) ? xa : ((q == 2) ? bias4 : zero4);
            f32x4 accR0 = __builtin_amdgcn_mfma_f32_16x16x16f16(a2, xfR[0], z4, 0, 0, 0);
            f32x4 accZ0 = __builtin_amdgcn_mfma_f32_16x16x16f16(a2, xfZ[0], z4, 0, 0, 0);
            f32x4 gin0  = __builtin_amdgcn_mfma_f32_16x16x16f16(a2, xfN[0], z4, 0, 0, 0);
            f32x4 accR1 = __builtin_amdgcn_mfma_f32_16x16x16f16(a2, xfR[1], z4, 0, 0, 0);
            f32x4 accZ1 = __builtin_amdgcn_mfma_f32_16x16x16f16(a2, xfZ[1], z4, 0, 0, 0);
            f32x4 gin1  = __builtin_amdgcn_mfma_f32_16x16x16f16(a2, xfN[1], z4, 0, 0, 0);
            f32x4 accN0 = z4, accN1 = z4;
            // fused 6-chain interleave (R9 structure); Z1 from wzv regs
            // (loaded LAST step; barrier already drained vmcnt -> no wait)
#pragma unroll
            for (int s = 0; s < 8; ++s) {
                const h8_t a  = *(const h8_t*)(hb + s * 32 + q * 8);
                const h8_t wn = wn_l[s * 64];
                accR0 = __builtin_amdgcn_mfma_f32_16x16x32_f16(a, wfR0[s], accR0, 0, 0, 0);
                accZ0 = __builtin_amdgcn_mfma_f32_16x16x32_f16(a, wfZ0[s], accZ0, 0, 0, 0);
                accN0 = __builtin_amdgcn_mfma_f32_16x16x32_f16(a, wfN0[s], accN0, 0, 0, 0);
                accR1 = __builtin_amdgcn_mfma_f32_16x16x32_f16(a, wfR1[s], accR1, 0, 0, 0);
                accZ1 = __builtin_amdgcn_mfma_f32_16x16x32_f16(a, wzv[s],  accZ1, 0, 0, 0);
                accN1 = __builtin_amdgcn_mfma_f32_16x16x32_f16(a, wn,      accN1, 0, 0, 0);
            }

            // reissue Z1 loads for the NEXT step: gate tail (~300cyc) covers
            // L2 latency; barrier vmcnt(0) drain then costs ~0. The barrier
            // fence prevents CSE/sinking of these loads.
#pragma unroll
            for (int s = 0; s < 8; ++s) wzv[s] = wz_g[s * 64];

            // pred_{t-1} (VALU-only DPP reduce; reads stable hbuf[cur])
            if (t > 0) {
                const h4_t hv4 = *(const h4_t*)(cur ? pr1 : pr0);
                float s0 = (float)hv4[0] * wl0 + (float)hv4[1] * wl1
                         + (float)hv4[2] * wl2 + (float)hv4[3] * wl3;
                s0 = wave_sum64(s0);
                if (lane == 63) predbuf[((t - 1) >> 6) & 1][w][(t - 1) & 63] = s0 + blin;
            }

            // gate tail, dense packed (lanes 0-31 g0, 32-63 g1); no mirror
            _Float16* __restrict__ hw = cur ? hw0 : hw1;   // write buf nxt=cur^1
#pragma unroll
            for (int j = 0; j < 4; ++j) {
                const float vR = hi ? accR1[j] : accR0[j];
                const float vZ = hi ? accZ1[j] : accZ0[j];
                const float vN = hi ? accN1[j] : accN0[j];
                const float vG = hi ? gin1[j]  : gin0[j];
                const float rr = __builtin_amdgcn_rcpf(1.f + __builtin_amdgcn_exp2f(vR));
                const float zz = __builtin_amdgcn_rcpf(1.f + __builtin_amdgcn_exp2f(vZ));
                const float u  = vG + rr * (vN + bhnp);
                const float nn = 1.f - 2.f * __builtin_amdgcn_rcpf(1.f + __builtin_amdgcn_exp2f(u));
                const float hv = nn + zz * (hreg[j] - nn);
                hreg[j] = hv;
                hw[j * ST] = (_Float16)hv;
            }

            // x window writeback (load issued at tw start; vmcnt hidden)
            if (ti == 15 && tw < 31) {
                xs_wr[0] = (_Float16)xpre[0];
                xs_wr[1] = (_Float16)xpre[1];
            }

            __syncthreads();   // single barrier per step

            // coalesced pred flush: one 2KB store per 64 steps
            if (ti == 0 && (tw & 3) == 0 && tw > 0) {
                const int pb = ((t >> 6) & 1) ^ 1;
                out[(size_t)(row0 + (tid >> 6)) * TT + (t - 64) + (tid & 63)] =
                    predbuf[pb][tid >> 6][tid & 63];
            }
        }
        xrp += 16 * II;
    }

    // final pred for t = TT-1 (h_final in hbuf[0])
    {
        const h4_t hv4 = *(const h4_t*)pr0;
        float s0 = (float)hv4[0] * wl0 + (float)hv4[1] * wl1
                 + (float)hv4[2] * wl2 + (float)hv4[3] * wl3;
        s0 = wave_sum64(s0);
        if (lane == 63) predbuf[1][w][63] = s0 + blin;
    }
    __syncthreads();
    // flush last chunk [448, 512)
    out[(size_t)(row0 + (tid >> 6)) * TT + 448 + (tid & 63)] =
        predbuf[1][tid >> 6][tid & 63];
}

extern "C" void kernel_launch(void* const* d_in, const int* in_sizes, int n_in,
                              void* d_out, int out_size, void* d_ws, size_t ws_size,
                              hipStream_t stream) {
    const float* x     = (const float*)d_in[0];
    const float* W_ih  = (const float*)d_in[1];
    const float* W_hh  = (const float*)d_in[2];
    const float* b_ih  = (const float*)d_in[3];
    const float* b_hh  = (const float*)d_in[4];
    const float* W_lin = (const float*)d_in[5];
    const float* b_lin = (const float*)d_in[6];
    float* out = (float*)d_out;
    // ws: 8*8*64 h8 fragments = 64 KiB (Z1 W pool, L2-resident)
    gru_kernel<<<NB, 512, 0, stream>>>(x, W_ih, W_hh, b_ih, b_hh, W_lin, b_lin, out,
                                       (h8_t*)d_ws);
}